// Round 5
// baseline (608.959 us; speedup 1.0000x reference)
//
#include <hip/hip_runtime.h>
#include <stddef.h>

#define NT 512       // timesteps
#define NI 28        // input dim
#define NH 64        // hidden dim
#define BT 4         // batch rows per block (4x dup into 16 MFMA rows)
#define CH 16        // x timesteps per staged chunk
#define XPh 36       // halfs per (t,b) x row: 28 payload + pad(28..35); pad[28]=1.0 (bias col)
#define HPh 72       // halfs per h row: 64 payload + 8 pad -> 144B (36-dw bank stride)
#define NTH 512      // 8 waves: 0-3 layer0, 4-7 layer1
#define XLD (CH*BT*7) // float4 loads per x chunk = 448

typedef _Float16 f16x8 __attribute__((ext_vector_type(8)));
typedef float    f32x4 __attribute__((ext_vector_type(4)));

__device__ __forceinline__ float sigm(float v)  { return __builtin_amdgcn_rcpf(1.f + __expf(-v)); }
__device__ __forceinline__ float tanh_(float v) { return 1.f - 2.f * __builtin_amdgcn_rcpf(__expf(2.f * v) + 1.f); }

// select element q (0..3) of an f32x4 with compile-time indices only (rule #20)
__device__ __forceinline__ float sel4(f32x4 a, int q) {
    return q == 0 ? a[0] : (q == 1 ? a[1] : (q == 2 ? a[2] : a[3]));
}

// LDS-only barrier: cross-wave communication in the main loops is exclusively
// through LDS, so lgkmcnt(0)+s_barrier suffices; in-flight global prefetch
// (VGPR dest) stays in flight across barriers, guarded by compiler vmcnt at use.
__device__ __forceinline__ void bar_lds() {
    asm volatile("s_waitcnt lgkmcnt(0)\n\ts_barrier" ::: "memory");
}

// flat x-chunk index [0,XLD) -> global float4 index
__device__ __forceinline__ size_t gxi(int idx, int n0, int b0) {
    int b   = idx / (CH * 7);
    int rem = idx - b * (CH * 7);
    int t   = rem / 7;
    int w7  = rem - t * 7;
    return ((size_t)(b0 + b) * NT + (n0 + t)) * 7 + w7;
}
// convert float4 -> f16x4, store into x chunk buffer
__device__ __forceinline__ void xstoreh(_Float16* dst, int idx, float4 v) {
    int b   = idx / (CH * 7);
    int rem = idx - b * (CH * 7);
    int t   = rem / 7;
    int w7  = rem - t * 7;
    _Float16* row = dst + (t * BT + b) * XPh;
    _Float16 tmp[4] = { (_Float16)v.x, (_Float16)v.y, (_Float16)v.z, (_Float16)v.w };
    *(uint2*)(row + 4 * w7) = *(const uint2*)tmp;
}

__global__ __launch_bounds__(NTH, 4)
void lstm2_mfma(const float* __restrict__ x,
                const float* __restrict__ Wih0, const float* __restrict__ Whh0,
                const float* __restrict__ bih0, const float* __restrict__ bhh0,
                const float* __restrict__ Wih1, const float* __restrict__ Whh1,
                const float* __restrict__ bih1, const float* __restrict__ bhh1,
                const float* __restrict__ Wout, const float* __restrict__ bout,
                float* __restrict__ out, float* __restrict__ rlast)
{
    __shared__ __align__(16) _Float16 s_x[2][CH * BT * XPh];  // double-buffered x (f16)
    __shared__ __align__(16) _Float16 s_h0[2][BT * HPh];      // h0 parity buffers
    __shared__ __align__(16) _Float16 s_h1[2][BT * HPh];      // h1 parity buffers
    __shared__ __align__(16) float    s_hf[BT * NH];          // fp32 h1(T-1) for head

    const int tid = threadIdx.x;
    const int ln  = tid & 63;
    const int wv  = tid >> 6;
    const int lay = wv >> 2;          // 0: layer0 waves, 1: layer1 waves
    const int w4  = wv & 3;           // 16-unit slice within the layer
    const int b0  = blockIdx.x * BT;

    const int colB = ln & 15;         // B/D column within tile
    const int q    = ln >> 4;         // lane quadrant: k offset, and owned batch
    const int kq   = q * 8;           // k offset of this lane's 8 A/B elements
    const int bA   = ln & 3;          // A batch row (rows 4..15 duplicate 0..3)
    const int ue   = w4 * 16 + colB;  // hidden unit of this lane's tile column
    const int offh = q * HPh + ue;    // h write offset: batch q, unit ue

    // ---------------- prologue: zero LDS, bias column, stage x chunk 0 ----------------
    #pragma unroll 1
    for (int i = tid; i < (int)(sizeof(s_x) / 4); i += NTH) ((int*)s_x)[i] = 0;
    #pragma unroll 1
    for (int i = tid; i < (int)((sizeof(s_h0) + sizeof(s_h1)) / 4); i += NTH) ((int*)s_h0)[i] = 0;
    __syncthreads();                       // zeroing visible before pad-col writes
    if (tid < 2 * CH * BT) {               // set x pad column k=28 to 1.0 (bias input)
        int buf = tid >> 6, r = tid & 63;
        s_x[buf][r * XPh + 28] = (_Float16)1.0f;
    }

    const float4* xg4 = (const float4*)x;
    if (tid < XLD) {
        float4 v = xg4[gxi(tid, 0, b0)];
        xstoreh(s_x[0], tid, v);
    }
    __syncthreads();

    const f32x4 z4 = { 0.f, 0.f, 0.f, 0.f };
    float cc0 = 0.f;                   // this lane's cell state (batch q, unit ue)
    float4 pfA;                        // x prefetch register

    if (lay == 0) {
        // ---- B fragments, layer0 (f16): chunks {x(+bias col), h0[0:32), h0[32:64)} ----
        f16x8 B0[4], B1[4], B2[4];
        #pragma unroll
        for (int t = 0; t < 4; ++t) {
            const int g = 64 * t + ue;
            const float bias0 = bih0[g] + bhh0[g];
            #pragma unroll
            for (int j = 0; j < 8; ++j) {
                int k = kq + j;
                float w0 = (k < NI) ? Wih0[g * NI + k] : (k == 28 ? bias0 : 0.f);
                B0[t][j] = (_Float16)w0;
                B1[t][j] = (_Float16)Whh0[g * NH + k];
                B2[t][j] = (_Float16)Whh0[g * NH + 32 + k];
            }
        }
        f32x4 accx[4];   // x-part of gates, computed one step ahead (barrier shadow)
        #pragma unroll 1
        for (int n = 0; n <= NT; ++n) {
            if ((n & 15) == 0 && n + CH < NT && tid < XLD)
                pfA = xg4[gxi(tid, n + CH, b0)];
            if (n < NT) {
                if ((n & 15) == 0) {   // chunk-start: x-part not hoisted, compute in-step
                    const _Float16* xrow = s_x[(n >> 4) & 1] + ((n & 15) * BT + bA) * XPh;
                    f16x8 Ax = *(const f16x8*)(xrow + kq);
                    #pragma unroll
                    for (int t = 0; t < 4; ++t)
                        accx[t] = __builtin_amdgcn_mfma_f32_16x16x32_f16(Ax, B0[t], z4, 0, 0, 0);
                }
                const _Float16* h0r = s_h0[(n - 1) & 1] + bA * HPh;
                f16x8 A0 = *(const f16x8*)(h0r + kq);
                f16x8 A1 = *(const f16x8*)(h0r + 32 + kq);
                f32x4 acc[4];
                #pragma unroll
                for (int t = 0; t < 4; ++t) {   // post-barrier chain: depth 2
                    f32x4 a = __builtin_amdgcn_mfma_f32_16x16x32_f16(A0, B1[t], accx[t], 0, 0, 0);
                    acc[t]  = __builtin_amdgcn_mfma_f32_16x16x32_f16(A1, B2[t], a, 0, 0, 0);
                }
                // single-cell EW: this lane owns (batch q, unit ue); bias via x pad col
                float g0 = sel4(acc[0], q);
                float g1 = sel4(acc[1], q);
                float g2 = sel4(acc[2], q);
                float g3 = sel4(acc[3], q);
                cc0 = sigm(g1) * cc0 + sigm(g0) * tanh_(g2);
                s_h0[n & 1][offh] = (_Float16)(sigm(g3) * tanh_(cc0));
                // hoist next step's x-part into the barrier shadow (x stable within
                // a chunk; skip at chunk boundary where buffer is rewritten)
                if ((n & 15) != 15 && n + 1 < NT) {
                    const _Float16* xrow2 = s_x[((n + 1) >> 4) & 1] + (((n + 1) & 15) * BT + bA) * XPh;
                    f16x8 Ax2 = *(const f16x8*)(xrow2 + kq);
                    #pragma unroll
                    for (int t = 0; t < 4; ++t)
                        accx[t] = __builtin_amdgcn_mfma_f32_16x16x32_f16(Ax2, B0[t], z4, 0, 0, 0);
                }
            }
            if ((n & 15) == 15 && n + 1 < NT && tid < XLD)
                xstoreh(s_x[((n >> 4) + 1) & 1], tid, pfA);
            bar_lds();
        }
    } else {
        // ---- B fragments, layer1 (f16): chunks {h0[0:32), h0[32:64), h1[0:32), h1[32:64)} ----
        f16x8 B0[4], B1[4], B2[4], B3[4]; f32x4 bseed[4];
        #pragma unroll
        for (int t = 0; t < 4; ++t) {
            const int g = 64 * t + ue;
            const float bf = bih1[g] + bhh1[g];
            bseed[t] = (f32x4){ bf, bf, bf, bf };   // bias seeded as MFMA C-operand
            #pragma unroll
            for (int j = 0; j < 8; ++j) {
                int k = kq + j;
                B0[t][j] = (_Float16)Wih1[g * NH + k];
                B1[t][j] = (_Float16)Wih1[g * NH + 32 + k];
                B2[t][j] = (_Float16)Whh1[g * NH + k];
                B3[t][j] = (_Float16)Whh1[g * NH + 32 + k];
            }
        }
        #pragma unroll 1
        for (int n = 0; n <= NT; ++n) {
            if ((n & 15) == 0 && n + CH < NT && tid < XLD)
                pfA = xg4[gxi(tid, n + CH, b0)];
            if (n >= 1) {
                const _Float16* h0r = s_h0[(n - 1) & 1] + bA * HPh;   // h0(n-1)
                const _Float16* h1r = s_h1[n & 1] + bA * HPh;         // h1(n-2)
                f16x8 A0 = *(const f16x8*)(h0r + kq);
                f16x8 A1 = *(const f16x8*)(h0r + 32 + kq);
                f16x8 A2 = *(const f16x8*)(h1r + kq);
                f16x8 A3 = *(const f16x8*)(h1r + 32 + kq);
                f32x4 acc[4];
                #pragma unroll
                for (int t = 0; t < 4; ++t) {   // depth-4 chain, bias-seeded (TLP hides latency)
                    f32x4 a = __builtin_amdgcn_mfma_f32_16x16x32_f16(A0, B0[t], bseed[t], 0, 0, 0);
                    a       = __builtin_amdgcn_mfma_f32_16x16x32_f16(A1, B1[t], a, 0, 0, 0);
                    a       = __builtin_amdgcn_mfma_f32_16x16x32_f16(A2, B2[t], a, 0, 0, 0);
                    acc[t]  = __builtin_amdgcn_mfma_f32_16x16x32_f16(A3, B3[t], a, 0, 0, 0);
                }
                float g0 = sel4(acc[0], q);
                float g1 = sel4(acc[1], q);
                float g2 = sel4(acc[2], q);
                float g3 = sel4(acc[3], q);
                cc0 = sigm(g1) * cc0 + sigm(g0) * tanh_(g2);
                float hv = sigm(g3) * tanh_(cc0);
                s_h1[(n - 1) & 1][offh] = (_Float16)hv;
                if (n == NT) {
                    rlast[(size_t)(b0 + q) * NH + ue] = hv;
                    s_hf[q * NH + ue] = hv;
                }
            }
            if ((n & 15) == 15 && n + 1 < NT && tid < XLD)
                xstoreh(s_x[((n >> 4) + 1) & 1], tid, pfA);
            bar_lds();
        }
    }

    // ---------------- head: out = r_last @ Wout.T + bout ----------------
    if (tid < BT * 10) {
        int b = tid / 10, o = tid - 10 * (tid / 10);
        float a = bout[o];
        #pragma unroll
        for (int u = 0; u < NH; ++u) a += Wout[o * NH + u] * s_hf[b * NH + u];
        out[(size_t)(b0 + b) * 10 + o] = a;
    }
}

extern "C" void kernel_launch(void* const* d_in, const int* in_sizes, int n_in,
                              void* d_out, int out_size, void* d_ws, size_t ws_size,
                              hipStream_t stream) {
    const float* x    = (const float*)d_in[0];
    const float* Wih0 = (const float*)d_in[1];
    const float* Whh0 = (const float*)d_in[2];
    const float* bih0 = (const float*)d_in[3];
    const float* bhh0 = (const float*)d_in[4];
    const float* Wih1 = (const float*)d_in[5];
    const float* Whh1 = (const float*)d_in[6];
    const float* bih1 = (const float*)d_in[7];
    const float* bhh1 = (const float*)d_in[8];
    const float* Wout = (const float*)d_in[9];
    const float* bout = (const float*)d_in[10];

    const int B = in_sizes[0] / (NT * NI);      // 2048
    float* out   = (float*)d_out;               // [B,10]
    float* rlast = out + (size_t)B * 10;        // [B,64]

    dim3 grid(B / BT), block(NTH);              // 512 blocks -> 2 blocks/CU
    hipLaunchKernelGGL(lstm2_mfma, grid, block, 0, stream,
                       x, Wih0, Whh0, bih0, bhh0, Wih1, Whh1, bih1, bhh1,
                       Wout, bout, out, rlast);
}

// Round 8
// 597.110 us; speedup vs baseline: 1.0198x; 1.0198x over previous
//
#include <hip/hip_runtime.h>
#include <stddef.h>

#define NT 512       // timesteps
#define NI 28        // input dim
#define NH 64        // hidden dim
#define BT 8         // batch rows per block (2x dup into 16 MFMA rows)
#define CH 16        // x timesteps per staged chunk
#define XPh 36       // halfs per (t,b) x row: 28 payload + pad(28..35); pad[28]=1.0 (bias col)
#define HPh 72       // halfs per h row: 64 payload + 8 pad -> 144B (36-dw bank stride)
#define NTH 512      // 8 waves: 0-3 layer0, 4-7 layer1
#define XLD (CH*BT*7) // float4 loads per x chunk = 896
#define LEAD 4       // max l0 lead over l1 (h0 ring depth)

typedef _Float16 f16x8 __attribute__((ext_vector_type(8)));
typedef float    f32x4 __attribute__((ext_vector_type(4)));

__device__ __forceinline__ float sigm(float v)  { return __builtin_amdgcn_rcpf(1.f + __expf(-v)); }
__device__ __forceinline__ float tanh_(float v) { return 1.f - 2.f * __builtin_amdgcn_rcpf(__expf(2.f * v) + 1.f); }

// flat x-chunk index [0,XLD) -> global float4 index
__device__ __forceinline__ size_t gxi(int idx, int n0, int b0) {
    int b   = idx / (CH * 7);
    int rem = idx - b * (CH * 7);
    int t   = rem / 7;
    int w7  = rem - t * 7;
    return ((size_t)(b0 + b) * NT + (n0 + t)) * 7 + w7;
}
// convert float4 -> f16x4, store into x chunk buffer
__device__ __forceinline__ void xstoreh(_Float16* dst, int idx, float4 v) {
    int b   = idx / (CH * 7);
    int rem = idx - b * (CH * 7);
    int t   = rem / 7;
    int w7  = rem - t * 7;
    _Float16* row = dst + (t * BT + b) * XPh;
    _Float16 tmp[4] = { (_Float16)v.x, (_Float16)v.y, (_Float16)v.z, (_Float16)v.w };
    *(uint2*)(row + 4 * w7) = *(const uint2*)tmp;
}

__global__ __launch_bounds__(NTH, 2)
void lstm2_mfma(const float* __restrict__ x,
                const float* __restrict__ Wih0, const float* __restrict__ Whh0,
                const float* __restrict__ bih0, const float* __restrict__ bhh0,
                const float* __restrict__ Wih1, const float* __restrict__ Whh1,
                const float* __restrict__ bih1, const float* __restrict__ bhh1,
                const float* __restrict__ Wout, const float* __restrict__ bout,
                float* __restrict__ out, float* __restrict__ rlast)
{
    __shared__ __align__(16) _Float16 s_x[2][CH * BT * XPh];  // double-buffered x (f16)
    __shared__ __align__(16) _Float16 s_h0[LEAD][BT * HPh];   // h0 ring (4-deep: l0 lead tolerance)
    __shared__ __align__(16) _Float16 s_h1[2][BT * HPh];      // h1 parity buffers
    __shared__ __align__(16) float    s_hf[BT * NH];          // fp32 h1(T-1) for head
    __shared__ __align__(16) int      s_fl[8];                // [0:4) l0 wave step flags, [4:8) l1

    const int tid = threadIdx.x;
    const int ln  = tid & 63;
    const int wv  = tid >> 6;
    const int lay = wv >> 2;          // 0: layer0 waves, 1: layer1 waves
    const int w4  = wv & 3;           // 16-unit slice within the layer
    const int b0  = blockIdx.x * BT;

    const int colB = ln & 15;         // B/D column within tile
    const int kq   = (ln >> 4) * 8;   // k offset of this lane's 8 A/B elements
    const int bA   = ln & 7;          // A batch row (rows 8-15 duplicate 0-7)
    const int ue   = w4 * 16 + colB;  // hidden unit of this lane's tile column
    const int m0   = (ln >> 4) * 4;   // first D row of this lane's fragment
    const int rq   = (ln >= 32) ? 2 : 0;        // acc pair handled by this lane
    const int bm0  = (m0 + rq) & 7;             // batch of cell 0
    const int bm1  = (m0 + rq + 1) & 7;         // batch of cell 1
    const bool hi  = (rq != 0);
    const int off0 = bm0 * HPh + ue;            // h write offsets
    const int off1 = bm1 * HPh + ue;

    // ---------------- prologue: zero LDS, flags, bias column, stage x chunk 0 ----------------
    #pragma unroll 1
    for (int i = tid; i < (int)(sizeof(s_x) / 4); i += NTH) ((int*)s_x)[i] = 0;
    #pragma unroll 1
    for (int i = tid; i < (int)(sizeof(s_h0) / 4); i += NTH) ((int*)s_h0)[i] = 0;
    #pragma unroll 1
    for (int i = tid; i < (int)(sizeof(s_h1) / 4); i += NTH) ((int*)s_h1)[i] = 0;
    if (tid < 8) s_fl[tid] = -1;
    __syncthreads();                       // zeroing visible before pad-col writes
    if (tid < 2 * CH * BT) {               // set x pad column k=28 to 1.0 (bias input)
        int buf = tid >> 7, r = tid & 127;
        s_x[buf][r * XPh + 28] = (_Float16)1.0f;
    }

    const float4* xg4 = (const float4*)x;
    {
        float4 v = xg4[gxi(tid, 0, b0)];
        xstoreh(s_x[0], tid, v);
        if (tid < XLD - NTH) {
            float4 v2 = xg4[gxi(tid + NTH, 0, b0)];
            xstoreh(s_x[0], tid + NTH, v2);
        }
    }
    __syncthreads();                       // last workgroup barrier before the head

    const f32x4 z4 = { 0.f, 0.f, 0.f, 0.f };
    float cc0 = 0.f, cc1 = 0.f;            // this lane's 2 cell states
    volatile int* fl0 = s_fl;              // l0 group flags
    volatile int* fl1 = s_fl + 4;          // l1 group flags

    if (lay == 0) {
        // ---- B fragments, layer0 (f16): chunks {x(+bias col), h0[0:32), h0[32:64)} ----
        f16x8 B0[4], B1[4], B2[4];
        #pragma unroll
        for (int t = 0; t < 4; ++t) {
            const int g = 64 * t + ue;
            const float bias0 = bih0[g] + bhh0[g];
            #pragma unroll
            for (int j = 0; j < 8; ++j) {
                int k = kq + j;
                float w0 = (k < NI) ? Wih0[g * NI + k] : (k == 28 ? bias0 : 0.f);
                B0[t][j] = (_Float16)w0;
                B1[t][j] = (_Float16)Whh0[g * NH + k];
                B2[t][j] = (_Float16)Whh0[g * NH + 32 + k];
            }
        }
        float4 pf0, pf1, pf2, pf3;         // x prefetch registers (l0 lanes: tid 0..255)
        f32x4 accx[4];                     // x-part of gates, one step ahead
        #pragma unroll 1
        for (int n = 0; n < NT; ++n) {
            // issue global prefetch before any waiting (HBM latency overlaps spin)
            if ((n & 15) == 0 && n + CH < NT) {
                pf0 = xg4[gxi(tid,       n + CH, b0)];
                pf1 = xg4[gxi(tid + 256, n + CH, b0)];
                pf2 = xg4[gxi(tid + 512, n + CH, b0)];
                if (tid < XLD - 768) pf3 = xg4[gxi(tid + 768, n + CH, b0)];
            }
            // wait: peers done n-1 (intra-group) AND l1 done >= n-LEAD (ring backpressure)
            for (;;) {
                int a0 = fl0[0], a1 = fl0[1], a2 = fl0[2], a3 = fl0[3];
                int c0 = fl1[0], c1 = fl1[1], c2 = fl1[2], c3 = fl1[3];
                int mn0 = min(min(a0, a1), min(a2, a3));
                int mn1 = min(min(c0, c1), min(c2, c3));
                if (mn0 >= n - 1 && mn1 >= n - LEAD) break;
                __builtin_amdgcn_s_sleep(1);
            }
            asm volatile("" ::: "memory");
            if ((n & 15) == 0) {   // chunk-start: x-part not hoisted, compute in-step
                const _Float16* xrow = s_x[(n >> 4) & 1] + ((n & 15) * BT + bA) * XPh;
                f16x8 Ax = *(const f16x8*)(xrow + kq);
                #pragma unroll
                for (int t = 0; t < 4; ++t)
                    accx[t] = __builtin_amdgcn_mfma_f32_16x16x32_f16(Ax, B0[t], z4, 0, 0, 0);
            }
            const _Float16* h0r = s_h0[(n - 1) & (LEAD - 1)] + bA * HPh;
            f16x8 A0 = *(const f16x8*)(h0r + kq);
            f16x8 A1 = *(const f16x8*)(h0r + 32 + kq);
            f32x4 acc[4];
            #pragma unroll
            for (int t = 0; t < 4; ++t) {   // post-wait chain: depth 2
                f32x4 a = __builtin_amdgcn_mfma_f32_16x16x32_f16(A0, B1[t], accx[t], 0, 0, 0);
                acc[t]  = __builtin_amdgcn_mfma_f32_16x16x32_f16(A1, B2[t], a, 0, 0, 0);
            }
            float g00 = hi ? acc[0][2] : acc[0][0];
            float g10 = hi ? acc[1][2] : acc[1][0];
            float g20 = hi ? acc[2][2] : acc[2][0];
            float g30 = hi ? acc[3][2] : acc[3][0];
            float g01 = hi ? acc[0][3] : acc[0][1];
            float g11 = hi ? acc[1][3] : acc[1][1];
            float g21 = hi ? acc[2][3] : acc[2][1];
            float g31 = hi ? acc[3][3] : acc[3][1];
            _Float16* hw = s_h0[n & (LEAD - 1)];
            cc0 = sigm(g10) * cc0 + sigm(g00) * tanh_(g20);
            hw[off0] = (_Float16)(sigm(g30) * tanh_(cc0));
            cc1 = sigm(g11) * cc1 + sigm(g01) * tanh_(g21);
            hw[off1] = (_Float16)(sigm(g31) * tanh_(cc1));
            // hoist next step's x-part (x stable within chunk; skip at boundary)
            if ((n & 15) != 15 && n + 1 < NT) {
                const _Float16* xrow2 = s_x[((n + 1) >> 4) & 1] + (((n + 1) & 15) * BT + bA) * XPh;
                f16x8 Ax2 = *(const f16x8*)(xrow2 + kq);
                #pragma unroll
                for (int t = 0; t < 4; ++t)
                    accx[t] = __builtin_amdgcn_mfma_f32_16x16x32_f16(Ax2, B0[t], z4, 0, 0, 0);
            }
            if ((n & 15) == 15 && n + 1 < NT) {   // stage next chunk (l0 lanes only)
                _Float16* dst = s_x[((n >> 4) + 1) & 1];
                xstoreh(dst, tid,       pf0);
                xstoreh(dst, tid + 256, pf1);
                xstoreh(dst, tid + 512, pf2);
                if (tid < XLD - 768) xstoreh(dst, tid + 768, pf3);
            }
            // publish: all LDS writes drained, then flag
            asm volatile("s_waitcnt lgkmcnt(0)" ::: "memory");
            if (ln == 0) *(volatile int*)&s_fl[w4] = n;
        }
    } else {
        // ---- B fragments, layer1 (f16): chunks {h0[0:32), h0[32:64), h1[0:32), h1[32:64)} ----
        f16x8 B0[4], B1[4], B2[4], B3[4]; f32x4 bseed[4];
        #pragma unroll
        for (int t = 0; t < 4; ++t) {
            const int g = 64 * t + ue;
            const float bf = bih1[g] + bhh1[g];
            bseed[t] = (f32x4){ bf, bf, bf, bf };   // bias seeded as MFMA C-operand
            #pragma unroll
            for (int j = 0; j < 8; ++j) {
                int k = kq + j;
                B0[t][j] = (_Float16)Wih1[g * NH + k];
                B1[t][j] = (_Float16)Wih1[g * NH + 32 + k];
                B2[t][j] = (_Float16)Whh1[g * NH + k];
                B3[t][j] = (_Float16)Whh1[g * NH + 32 + k];
            }
        }
        #pragma unroll 1
        for (int m = 0; m < NT; ++m) {     // computes h1(m)
            // wait: l0 done step m (h0(m) ready) AND peers done m-1 (h1(m-1) ready)
            for (;;) {
                int a0 = fl0[0], a1 = fl0[1], a2 = fl0[2], a3 = fl0[3];
                int c0 = fl1[0], c1 = fl1[1], c2 = fl1[2], c3 = fl1[3];
                int mn0 = min(min(a0, a1), min(a2, a3));
                int mn1 = min(min(c0, c1), min(c2, c3));
                if (mn0 >= m && mn1 >= m - 1) break;
                __builtin_amdgcn_s_sleep(1);
            }
            asm volatile("" ::: "memory");
            const _Float16* h0r = s_h0[m & (LEAD - 1)] + bA * HPh;  // h0(m)
            const _Float16* h1r = s_h1[(m + 1) & 1] + bA * HPh;     // h1(m-1)
            f16x8 A0 = *(const f16x8*)(h0r + kq);
            f16x8 A1 = *(const f16x8*)(h0r + 32 + kq);
            f16x8 A2 = *(const f16x8*)(h1r + kq);
            f16x8 A3 = *(const f16x8*)(h1r + 32 + kq);
            f32x4 accp[4], accq[4];
            #pragma unroll
            for (int t = 0; t < 4; ++t) {   // two independent depth-2 chains
                f32x4 p = __builtin_amdgcn_mfma_f32_16x16x32_f16(A0, B0[t], bseed[t], 0, 0, 0);
                accp[t] = __builtin_amdgcn_mfma_f32_16x16x32_f16(A1, B1[t], p, 0, 0, 0);
                f32x4 qq = __builtin_amdgcn_mfma_f32_16x16x32_f16(A2, B2[t], z4, 0, 0, 0);
                accq[t] = __builtin_amdgcn_mfma_f32_16x16x32_f16(A3, B3[t], qq, 0, 0, 0);
            }
            float g00 = (hi ? accp[0][2] : accp[0][0]) + (hi ? accq[0][2] : accq[0][0]);
            float g10 = (hi ? accp[1][2] : accp[1][0]) + (hi ? accq[1][2] : accq[1][0]);
            float g20 = (hi ? accp[2][2] : accp[2][0]) + (hi ? accq[2][2] : accq[2][0]);
            float g30 = (hi ? accp[3][2] : accp[3][0]) + (hi ? accq[3][2] : accq[3][0]);
            float g01 = (hi ? accp[0][3] : accp[0][1]) + (hi ? accq[0][3] : accq[0][1]);
            float g11 = (hi ? accp[1][3] : accp[1][1]) + (hi ? accq[1][3] : accq[1][1]);
            float g21 = (hi ? accp[2][3] : accp[2][1]) + (hi ? accq[2][3] : accq[2][1]);
            float g31 = (hi ? accp[3][3] : accp[3][1]) + (hi ? accq[3][3] : accq[3][1]);
            _Float16* hw = s_h1[m & 1];
            cc0 = sigm(g10) * cc0 + sigm(g00) * tanh_(g20);
            float h0v = sigm(g30) * tanh_(cc0);
            hw[off0] = (_Float16)h0v;
            cc1 = sigm(g11) * cc1 + sigm(g01) * tanh_(g21);
            float h1v = sigm(g31) * tanh_(cc1);
            hw[off1] = (_Float16)h1v;
            if (m == NT - 1) {
                rlast[(size_t)(b0 + bm0) * NH + ue] = h0v;
                rlast[(size_t)(b0 + bm1) * NH + ue] = h1v;
                s_hf[bm0 * NH + ue] = h0v;
                s_hf[bm1 * NH + ue] = h1v;
            }
            asm volatile("s_waitcnt lgkmcnt(0)" ::: "memory");
            if (ln == 0) *(volatile int*)&s_fl[4 + w4] = m;
        }
    }

    __syncthreads();   // l1's s_hf visible to head lanes

    // ---------------- head: out = r_last @ Wout.T + bout ----------------
    if (tid < BT * 10) {
        int b = tid / 10, o = tid - 10 * (tid / 10);
        float a = bout[o];
        #pragma unroll
        for (int u = 0; u < NH; ++u) a += Wout[o * NH + u] * s_hf[b * NH + u];
        out[(size_t)(b0 + b) * 10 + o] = a;
    }
}

extern "C" void kernel_launch(void* const* d_in, const int* in_sizes, int n_in,
                              void* d_out, int out_size, void* d_ws, size_t ws_size,
                              hipStream_t stream) {
    const float* x    = (const float*)d_in[0];
    const float* Wih0 = (const float*)d_in[1];
    const float* Whh0 = (const float*)d_in[2];
    const float* bih0 = (const float*)d_in[3];
    const float* bhh0 = (const float*)d_in[4];
    const float* Wih1 = (const float*)d_in[5];
    const float* Whh1 = (const float*)d_in[6];
    const float* bih1 = (const float*)d_in[7];
    const float* bhh1 = (const float*)d_in[8];
    const float* Wout = (const float*)d_in[9];
    const float* bout = (const float*)d_in[10];

    const int B = in_sizes[0] / (NT * NI);      // 2048
    float* out   = (float*)d_out;               // [B,10]
    float* rlast = out + (size_t)B * 10;        // [B,64]

    dim3 grid(B / BT), block(NTH);              // 256 blocks -> 1 block/CU
    hipLaunchKernelGGL(lstm2_mfma, grid, block, 0, stream,
                       x, Wih0, Whh0, bih0, bhh0, Wih1, Whh1, bih1, bhh1,
                       Wout, bout, out, rlast);
}

// Round 11
// 489.776 us; speedup vs baseline: 1.2433x; 1.2191x over previous
//
#include <hip/hip_runtime.h>
#include <stddef.h>

#define NT 512       // timesteps
#define NI 28        // input dim
#define NH 64        // hidden dim
#define BT 8         // batch rows per block (2x dup into 16 MFMA rows)
#define CH 16        // x timesteps per staged chunk
#define XPh 36       // halfs per (t,b) x row: 28 payload + pad(28..35); pad[28]=1.0 (bias col)
#define HPh 72       // halfs per h row: 64 payload + 8 pad -> 144B (36-dw bank stride)
#define NTH 512      // 8 waves: 0-3 layer0, 4-7 layer1
#define XLD (CH*BT*7) // float4 loads per x chunk = 896

typedef _Float16 f16x8 __attribute__((ext_vector_type(8)));
typedef float    f32x4 __attribute__((ext_vector_type(4)));

__device__ __forceinline__ float sigm(float v)  { return __builtin_amdgcn_rcpf(1.f + __expf(-v)); }
__device__ __forceinline__ float tanh_(float v) { return 1.f - 2.f * __builtin_amdgcn_rcpf(__expf(2.f * v) + 1.f); }

// LDS-only barrier: cross-wave communication in the main loop is exclusively
// through LDS, so lgkmcnt(0)+s_barrier suffices; in-flight global prefetch
// (VGPR dest) stays pending across barriers, guarded by compiler vmcnt at use.
__device__ __forceinline__ void bar_lds() {
    asm volatile("s_waitcnt lgkmcnt(0)\n\ts_barrier" ::: "memory");
}

// flat x-chunk index [0,XLD) -> global float4 index
__device__ __forceinline__ size_t gxi(int idx, int n0, int b0) {
    int b   = idx / (CH * 7);
    int rem = idx - b * (CH * 7);
    int t   = rem / 7;
    int w7  = rem - t * 7;
    return ((size_t)(b0 + b) * NT + (n0 + t)) * 7 + w7;
}
// convert float4 -> f16x4, store into x chunk buffer
__device__ __forceinline__ void xstoreh(_Float16* dst, int idx, float4 v) {
    int b   = idx / (CH * 7);
    int rem = idx - b * (CH * 7);
    int t   = rem / 7;
    int w7  = rem - t * 7;
    _Float16* row = dst + (t * BT + b) * XPh;
    _Float16 tmp[4] = { (_Float16)v.x, (_Float16)v.y, (_Float16)v.z, (_Float16)v.w };
    *(uint2*)(row + 4 * w7) = *(const uint2*)tmp;
}

__global__ __launch_bounds__(NTH, 2)
void lstm2_mfma(const float* __restrict__ x,
                const float* __restrict__ Wih0, const float* __restrict__ Whh0,
                const float* __restrict__ bih0, const float* __restrict__ bhh0,
                const float* __restrict__ Wih1, const float* __restrict__ Whh1,
                const float* __restrict__ bih1, const float* __restrict__ bhh1,
                const float* __restrict__ Wout, const float* __restrict__ bout,
                float* __restrict__ out, float* __restrict__ rlast)
{
    __shared__ __align__(16) _Float16 s_x[2][CH * BT * XPh];  // double-buffered x (f16)
    __shared__ __align__(16) _Float16 s_h0[2][BT * HPh];      // h0 parity buffers
    __shared__ __align__(16) _Float16 s_h1[2][BT * HPh];      // h1 parity buffers
    __shared__ __align__(16) float    s_hf[BT * NH];          // fp32 h1(T-1) for head

    const int tid = threadIdx.x;
    const int ln  = tid & 63;
    const int wv  = tid >> 6;
    const int lay = wv >> 2;          // 0: layer0 waves, 1: layer1 waves
    const int w4  = wv & 3;           // 16-unit slice within the layer
    const int b0  = blockIdx.x * BT;

    const int colB = ln & 15;         // B/D column within tile
    const int kq   = (ln >> 4) * 8;   // k offset of this lane's 8 A/B elements
    const int bA   = ln & 7;          // A batch row (rows 8-15 duplicate 0-7)
    const int ue   = w4 * 16 + colB;  // hidden unit of this lane's tile column
    const int m0   = (ln >> 4) * 4;   // first D row of this lane's fragment
    const int rq   = (ln >= 32) ? 2 : 0;        // acc pair handled by this lane
    const int bm0  = (m0 + rq) & 7;             // batch of cell 0
    const int bm1  = (m0 + rq + 1) & 7;         // batch of cell 1
    const bool hi  = (rq != 0);
    const int off0 = bm0 * HPh + ue;            // h write offsets
    const int off1 = bm1 * HPh + ue;

    // ---------------- prologue: zero LDS, bias column, stage x chunk 0 ----------------
    #pragma unroll 1
    for (int i = tid; i < (int)(sizeof(s_x) / 4); i += NTH) ((int*)s_x)[i] = 0;
    #pragma unroll 1
    for (int i = tid; i < (int)(sizeof(s_h0) / 4); i += NTH) ((int*)s_h0)[i] = 0;
    #pragma unroll 1
    for (int i = tid; i < (int)(sizeof(s_h1) / 4); i += NTH) ((int*)s_h1)[i] = 0;
    __syncthreads();                       // zeroing visible before pad-col writes
    if (tid < 2 * CH * BT) {               // set x pad column k=28 to 1.0 (bias input)
        int buf = tid >> 7, r = tid & 127;
        s_x[buf][r * XPh + 28] = (_Float16)1.0f;
    }

    const float4* xg4 = (const float4*)x;
    {
        float4 v = xg4[gxi(tid, 0, b0)];
        xstoreh(s_x[0], tid, v);
        if (tid < XLD - NTH) {
            float4 v2 = xg4[gxi(tid + NTH, 0, b0)];
            xstoreh(s_x[0], tid + NTH, v2);
        }
    }
    __syncthreads();

    const f32x4 z4 = { 0.f, 0.f, 0.f, 0.f };
    float cc0 = 0.f, cc1 = 0.f;            // this lane's 2 cell states

    if (lay == 0) {
        // ---- B fragments, layer0 (f16): chunks {x(+bias col), h0[0:32), h0[32:64)} ----
        f16x8 B0[4], B1[4], B2[4];
        #pragma unroll
        for (int t = 0; t < 4; ++t) {
            const int g = 64 * t + ue;
            const float bias0 = bih0[g] + bhh0[g];
            #pragma unroll
            for (int j = 0; j < 8; ++j) {
                int k = kq + j;
                float w0 = (k < NI) ? Wih0[g * NI + k] : (k == 28 ? bias0 : 0.f);
                B0[t][j] = (_Float16)w0;
                B1[t][j] = (_Float16)Whh0[g * NH + k];
                B2[t][j] = (_Float16)Whh0[g * NH + 32 + k];
            }
        }
        float4 pf0, pf1, pf2, pf3;         // x prefetch registers
        f32x4 acc[4];                      // gates0(n), persists sub1 -> sub2
        #pragma unroll 1
        for (int n = 0; n <= NT; ++n) {
            if (n < NT) {
                // -------- sub1: MFMA phase (l1 is doing EW on the VALU now) --------
                if ((n & 15) == 0 && n + CH < NT) {
                    pf0 = xg4[gxi(tid,       n + CH, b0)];
                    pf1 = xg4[gxi(tid + 256, n + CH, b0)];
                    pf2 = xg4[gxi(tid + 512, n + CH, b0)];
                    if (tid < XLD - 768) pf3 = xg4[gxi(tid + 768, n + CH, b0)];
                }
                const _Float16* xrow = s_x[(n >> 4) & 1] + ((n & 15) * BT + bA) * XPh;
                f16x8 Ax = *(const f16x8*)(xrow + kq);
                const _Float16* h0r = s_h0[(n - 1) & 1] + bA * HPh;
                f16x8 A0 = *(const f16x8*)(h0r + kq);
                f16x8 A1 = *(const f16x8*)(h0r + 32 + kq);
                #pragma unroll
                for (int t = 0; t < 4; ++t) {
                    f32x4 a = __builtin_amdgcn_mfma_f32_16x16x32_f16(Ax, B0[t], z4, 0, 0, 0);
                    a       = __builtin_amdgcn_mfma_f32_16x16x32_f16(A0, B1[t], a, 0, 0, 0);
                    acc[t]  = __builtin_amdgcn_mfma_f32_16x16x32_f16(A1, B2[t], a, 0, 0, 0);
                }
                bar_lds();
                // -------- sub2: EW phase (l1 is doing MFMA now) --------
                float g00 = hi ? acc[0][2] : acc[0][0];
                float g10 = hi ? acc[1][2] : acc[1][0];
                float g20 = hi ? acc[2][2] : acc[2][0];
                float g30 = hi ? acc[3][2] : acc[3][0];
                float g01 = hi ? acc[0][3] : acc[0][1];
                float g11 = hi ? acc[1][3] : acc[1][1];
                float g21 = hi ? acc[2][3] : acc[2][1];
                float g31 = hi ? acc[3][3] : acc[3][1];
                _Float16* hw = s_h0[n & 1];
                cc0 = sigm(g10) * cc0 + sigm(g00) * tanh_(g20);
                hw[off0] = (_Float16)(sigm(g30) * tanh_(cc0));
                cc1 = sigm(g11) * cc1 + sigm(g01) * tanh_(g21);
                hw[off1] = (_Float16)(sigm(g31) * tanh_(cc1));
                if ((n & 15) == 15 && n + 1 < NT) {   // stage next x chunk
                    _Float16* dst = s_x[((n >> 4) + 1) & 1];
                    xstoreh(dst, tid,       pf0);
                    xstoreh(dst, tid + 256, pf1);
                    xstoreh(dst, tid + 512, pf2);
                    if (tid < XLD - 768) xstoreh(dst, tid + 768, pf3);
                }
                bar_lds();
            } else {
                bar_lds();                 // n == NT: keep barrier count uniform
                bar_lds();
            }
        }
    } else {
        // ---- B fragments, layer1 (f16): chunks {h0[0:32), h0[32:64), h1[0:32), h1[32:64)} ----
        f16x8 B0[4], B1[4], B2[4], B3[4]; f32x4 bseed[4];
        #pragma unroll
        for (int t = 0; t < 4; ++t) {
            const int g = 64 * t + ue;
            const float bf = bih1[g] + bhh1[g];
            bseed[t] = (f32x4){ bf, bf, bf, bf };   // bias seeded as MFMA C-operand
            #pragma unroll
            for (int j = 0; j < 8; ++j) {
                int k = kq + j;
                B0[t][j] = (_Float16)Wih1[g * NH + k];
                B1[t][j] = (_Float16)Wih1[g * NH + 32 + k];
                B2[t][j] = (_Float16)Whh1[g * NH + k];
                B3[t][j] = (_Float16)Whh1[g * NH + 32 + k];
            }
        }
        f32x4 accp[4] = { z4, z4, z4, z4 };   // gates1(n-1), persists sub2 -> next sub1
        f32x4 accq[4] = { z4, z4, z4, z4 };
        #pragma unroll 1
        for (int n = 0; n <= NT; ++n) {
            // -------- sub1: EW of gates1(n-2) (l0 is doing MFMA now) --------
            if (n >= 2) {
                float g00 = (hi ? accp[0][2] : accp[0][0]) + (hi ? accq[0][2] : accq[0][0]);
                float g10 = (hi ? accp[1][2] : accp[1][0]) + (hi ? accq[1][2] : accq[1][0]);
                float g20 = (hi ? accp[2][2] : accp[2][0]) + (hi ? accq[2][2] : accq[2][0]);
                float g30 = (hi ? accp[3][2] : accp[3][0]) + (hi ? accq[3][2] : accq[3][0]);
                float g01 = (hi ? accp[0][3] : accp[0][1]) + (hi ? accq[0][3] : accq[0][1]);
                float g11 = (hi ? accp[1][3] : accp[1][1]) + (hi ? accq[1][3] : accq[1][1]);
                float g21 = (hi ? accp[2][3] : accp[2][1]) + (hi ? accq[2][3] : accq[2][1]);
                float g31 = (hi ? accp[3][3] : accp[3][1]) + (hi ? accq[3][3] : accq[3][1]);
                _Float16* hw = s_h1[(n - 2) & 1];   // h1(n-2)
                cc0 = sigm(g10) * cc0 + sigm(g00) * tanh_(g20);
                hw[off0] = (_Float16)(sigm(g30) * tanh_(cc0));
                cc1 = sigm(g11) * cc1 + sigm(g01) * tanh_(g21);
                hw[off1] = (_Float16)(sigm(g31) * tanh_(cc1));
            }
            bar_lds();
            // -------- sub2: MFMA gates1(n-1) (l0 is doing EW now) --------
            if (n >= 1) {
                const _Float16* h0r = s_h0[(n - 1) & 1] + bA * HPh;   // h0(n-1)
                const _Float16* h1r = s_h1[(n - 2) & 1] + bA * HPh;   // h1(n-2) (zeros for n==1)
                f16x8 A0 = *(const f16x8*)(h0r + kq);
                f16x8 A1 = *(const f16x8*)(h0r + 32 + kq);
                f16x8 A2 = *(const f16x8*)(h1r + kq);
                f16x8 A3 = *(const f16x8*)(h1r + 32 + kq);
                #pragma unroll
                for (int t = 0; t < 4; ++t) {   // two independent depth-2 chains
                    f32x4 p = __builtin_amdgcn_mfma_f32_16x16x32_f16(A0, B0[t], bseed[t], 0, 0, 0);
                    accp[t] = __builtin_amdgcn_mfma_f32_16x16x32_f16(A1, B1[t], p, 0, 0, 0);
                    f32x4 qq = __builtin_amdgcn_mfma_f32_16x16x32_f16(A2, B2[t], z4, 0, 0, 0);
                    accq[t] = __builtin_amdgcn_mfma_f32_16x16x32_f16(A3, B3[t], qq, 0, 0, 0);
                }
            }
            bar_lds();
        }
        // -------- final EW: gates1(NT-1) -> rlast + s_hf (no LDS h1 write needed) --------
        {
            float g00 = (hi ? accp[0][2] : accp[0][0]) + (hi ? accq[0][2] : accq[0][0]);
            float g10 = (hi ? accp[1][2] : accp[1][0]) + (hi ? accq[1][2] : accq[1][0]);
            float g20 = (hi ? accp[2][2] : accp[2][0]) + (hi ? accq[2][2] : accq[2][0]);
            float g30 = (hi ? accp[3][2] : accp[3][0]) + (hi ? accq[3][2] : accq[3][0]);
            float g01 = (hi ? accp[0][3] : accp[0][1]) + (hi ? accq[0][3] : accq[0][1]);
            float g11 = (hi ? accp[1][3] : accp[1][1]) + (hi ? accq[1][3] : accq[1][1]);
            float g21 = (hi ? accp[2][3] : accp[2][1]) + (hi ? accq[2][3] : accq[2][1]);
            float g31 = (hi ? accp[3][3] : accp[3][1]) + (hi ? accq[3][3] : accq[3][1]);
            cc0 = sigm(g10) * cc0 + sigm(g00) * tanh_(g20);
            float h0v = sigm(g30) * tanh_(cc0);
            cc1 = sigm(g11) * cc1 + sigm(g01) * tanh_(g21);
            float h1v = sigm(g31) * tanh_(cc1);
            rlast[(size_t)(b0 + bm0) * NH + ue] = h0v;
            rlast[(size_t)(b0 + bm1) * NH + ue] = h1v;
            s_hf[bm0 * NH + ue] = h0v;
            s_hf[bm1 * NH + ue] = h1v;
        }
    }

    __syncthreads();   // l1's s_hf visible to head lanes

    // ---------------- head: out = r_last @ Wout.T + bout ----------------
    if (tid < BT * 10) {
        int b = tid / 10, o = tid - 10 * (tid / 10);
        float a = bout[o];
        #pragma unroll
        for (int u = 0; u < NH; ++u) a += Wout[o * NH + u] * s_hf[b * NH + u];
        out[(size_t)(b0 + b) * 10 + o] = a;
    }
}

extern "C" void kernel_launch(void* const* d_in, const int* in_sizes, int n_in,
                              void* d_out, int out_size, void* d_ws, size_t ws_size,
                              hipStream_t stream) {
    const float* x    = (const float*)d_in[0];
    const float* Wih0 = (const float*)d_in[1];
    const float* Whh0 = (const float*)d_in[2];
    const float* bih0 = (const float*)d_in[3];
    const float* bhh0 = (const float*)d_in[4];
    const float* Wih1 = (const float*)d_in[5];
    const float* Whh1 = (const float*)d_in[6];
    const float* bih1 = (const float*)d_in[7];
    const float* bhh1 = (const float*)d_in[8];
    const float* Wout = (const float*)d_in[9];
    const float* bout = (const float*)d_in[10];

    const int B = in_sizes[0] / (NT * NI);      // 2048
    float* out   = (float*)d_out;               // [B,10]
    float* rlast = out + (size_t)B * 10;        // [B,64]

    dim3 grid(B / BT), block(NTH);              // 256 blocks -> 1 block/CU
    hipLaunchKernelGGL(lstm2_mfma, grid, block, 0, stream,
                       x, Wih0, Whh0, bih0, bhh0, Wih1, Whh1, bih1, bhh1,
                       Wout, bout, out, rlast);
}

// Round 12
// 469.266 us; speedup vs baseline: 1.2977x; 1.0437x over previous
//
#include <hip/hip_runtime.h>
#include <stddef.h>

#define NT 512       // timesteps
#define NI 28        // input dim
#define NH 64        // hidden dim
#define BT 8         // batch rows per block (2x dup into 16 MFMA rows)
#define CH 16        // x timesteps per staged chunk
#define XPh 36       // halfs per (t,b) x row: 28 payload + pad(28..35); pad[28]=1.0 (bias col)
#define HPh 72       // halfs per h row: 64 payload + 8 pad -> 144B (36-dw bank stride)
#define NTH 512      // 8 waves: 0-3 layer0, 4-7 layer1

typedef _Float16 f16x8 __attribute__((ext_vector_type(8)));
typedef float    f32x4 __attribute__((ext_vector_type(4)));

// 7-transcendental LSTM cell EW (vs 10 for naive sigm/tanh):
//   c' = sigm(gf)*c + sigm(gi)*tanh(gg) = [c*dBC + (C-1)*dA] / (dA*dBC)
//   h  = sigm(go)*tanh(c') = (E-1) / ((1+D)(E+1))
// where A=e^-gf, B=e^-gi, C=e^{2gg}, D=e^-go, E=e^{2c'} (E-arg clamped: for
// 2c'>80 this returns sigm(go), identical to the saturated tanh of the old form).
__device__ __forceinline__ float cell_ew(float gi, float gf, float gg, float go, float& cc) {
    float A = __expf(-gf), B = __expf(-gi), C = __expf(2.f * gg), D = __expf(-go);
    float dA  = 1.f + A;
    float dBC = (1.f + B) * (C + 1.f);
    float r   = __builtin_amdgcn_rcpf(dA * dBC);
    cc = r * (cc * dBC + (C - 1.f) * dA);
    float E = __expf(fminf(2.f * cc, 80.f));
    return (E - 1.f) * __builtin_amdgcn_rcpf((1.f + D) * (E + 1.f));
}

// LDS-only barrier: cross-wave communication in the main loops is exclusively
// through LDS, so lgkmcnt(0)+s_barrier suffices; in-flight global prefetch
// (VGPR dest) stays in flight across barriers, guarded by compiler vmcnt at use.
__device__ __forceinline__ void bar_lds() {
    asm volatile("s_waitcnt lgkmcnt(0)\n\ts_barrier" ::: "memory");
}

// flat x-chunk index [0,896) -> global float4 index
__device__ __forceinline__ size_t gxi(int idx, int n0, int b0) {
    int b   = idx / (CH * 7);
    int rem = idx - b * (CH * 7);
    int t   = rem / 7;
    int w7  = rem - t * 7;
    return ((size_t)(b0 + b) * NT + (n0 + t)) * 7 + w7;
}
// convert float4 -> f16x4, store into x chunk buffer
__device__ __forceinline__ void xstoreh(_Float16* dst, int idx, float4 v) {
    int b   = idx / (CH * 7);
    int rem = idx - b * (CH * 7);
    int t   = rem / 7;
    int w7  = rem - t * 7;
    _Float16* row = dst + (t * BT + b) * XPh;
    _Float16 tmp[4] = { (_Float16)v.x, (_Float16)v.y, (_Float16)v.z, (_Float16)v.w };
    *(uint2*)(row + 4 * w7) = *(const uint2*)tmp;
}

__global__ __launch_bounds__(NTH, 2)
void lstm2_mfma(const float* __restrict__ x,
                const float* __restrict__ Wih0, const float* __restrict__ Whh0,
                const float* __restrict__ bih0, const float* __restrict__ bhh0,
                const float* __restrict__ Wih1, const float* __restrict__ Whh1,
                const float* __restrict__ bih1, const float* __restrict__ bhh1,
                const float* __restrict__ Wout, const float* __restrict__ bout,
                float* __restrict__ out, float* __restrict__ rlast)
{
    __shared__ __align__(16) _Float16 s_x[2][CH * BT * XPh];  // double-buffered x (f16)
    __shared__ __align__(16) _Float16 s_h0[2][BT * HPh];      // h0 parity buffers
    __shared__ __align__(16) _Float16 s_h1[2][BT * HPh];      // h1 parity buffers
    __shared__ __align__(16) float    s_hf[BT * NH];          // fp32 h1(T-1) for head

    const int tid = threadIdx.x;
    const int ln  = tid & 63;
    const int wv  = tid >> 6;
    const int lay = wv >> 2;          // 0: layer0 waves, 1: layer1 waves
    const int w4  = wv & 3;           // 16-unit slice within the layer
    const int b0  = blockIdx.x * BT;

    const int colB = ln & 15;         // B/D column within tile
    const int kq   = (ln >> 4) * 8;   // k offset of this lane's 8 A/B elements
    const int bA   = ln & 7;          // A batch row (rows 8-15 duplicate 0-7)
    const int ue   = w4 * 16 + colB;  // hidden unit of this lane's tile column
    const int m0   = (ln >> 4) * 4;   // first D row of this lane's fragment
    const int rq   = (ln >= 32) ? 2 : 0;        // acc pair handled by this lane
    const int bm0  = (m0 + rq) & 7;             // batch of cell 0
    const int bm1  = (m0 + rq + 1) & 7;         // batch of cell 1
    const bool hi  = (rq != 0);
    const int off0 = bm0 * HPh + ue;            // h write offsets
    const int off1 = bm1 * HPh + ue;

    // ---------------- prologue: zero LDS, bias column, stage x chunk 0 ----------------
    #pragma unroll 1
    for (int i = tid; i < (int)(sizeof(s_x) / 4); i += NTH) ((int*)s_x)[i] = 0;
    #pragma unroll 1
    for (int i = tid; i < (int)((sizeof(s_h0) + sizeof(s_h1)) / 4); i += NTH) ((int*)s_h0)[i] = 0;
    __syncthreads();                       // zeroing visible before pad-col writes
    if (tid < 2 * CH * BT) {               // set x pad column k=28 to 1.0 (bias input)
        int buf = tid >> 7, r = tid & 127;
        s_x[buf][r * XPh + 28] = (_Float16)1.0f;
    }

    const float4* xg4 = (const float4*)x;
    {
        float4 v = xg4[gxi(tid, 0, b0)];
        xstoreh(s_x[0], tid, v);
        if (tid < 384) {
            float4 v2 = xg4[gxi(tid + NTH, 0, b0)];
            xstoreh(s_x[0], tid + NTH, v2);
        }
    }
    __syncthreads();

    const f32x4 z4 = { 0.f, 0.f, 0.f, 0.f };
    float cc0 = 0.f, cc1 = 0.f;        // this lane's 2 cell states
    float4 pfA, pfB;                   // x prefetch registers

    if (lay == 0) {
        // ---- B fragments, layer0 (f16): chunks {x(+bias col), h0[0:32), h0[32:64)} ----
        f16x8 B0[4], B1[4], B2[4];
        #pragma unroll
        for (int t = 0; t < 4; ++t) {
            const int g = 64 * t + ue;
            const float bias0 = bih0[g] + bhh0[g];
            #pragma unroll
            for (int j = 0; j < 8; ++j) {
                int k = kq + j;
                float w0 = (k < NI) ? Wih0[g * NI + k] : (k == 28 ? bias0 : 0.f);
                B0[t][j] = (_Float16)w0;
                B1[t][j] = (_Float16)Whh0[g * NH + k];
                B2[t][j] = (_Float16)Whh0[g * NH + 32 + k];
            }
        }
        f32x4 accx[4];   // x-part of gates, computed one step ahead (barrier shadow)
        #pragma unroll 1
        for (int n = 0; n <= NT; ++n) {
            if ((n & 15) == 0 && n + CH < NT) {
                pfA = xg4[gxi(tid, n + CH, b0)];
                if (tid < 384) pfB = xg4[gxi(tid + NTH, n + CH, b0)];
            }
            if (n < NT) {
                if ((n & 15) == 0) {   // chunk-start: x-part not hoisted, compute in-step
                    const _Float16* xrow = s_x[(n >> 4) & 1] + ((n & 15) * BT + bA) * XPh;
                    f16x8 Ax = *(const f16x8*)(xrow + kq);
                    #pragma unroll
                    for (int t = 0; t < 4; ++t)
                        accx[t] = __builtin_amdgcn_mfma_f32_16x16x32_f16(Ax, B0[t], z4, 0, 0, 0);
                }
                const _Float16* h0r = s_h0[(n - 1) & 1] + bA * HPh;
                f16x8 A0 = *(const f16x8*)(h0r + kq);
                f16x8 A1 = *(const f16x8*)(h0r + 32 + kq);
                f32x4 acc[4];
                #pragma unroll
                for (int t = 0; t < 4; ++t) {   // post-barrier chain: depth 2
                    f32x4 a = __builtin_amdgcn_mfma_f32_16x16x32_f16(A0, B1[t], accx[t], 0, 0, 0);
                    acc[t]  = __builtin_amdgcn_mfma_f32_16x16x32_f16(A1, B2[t], a, 0, 0, 0);
                }
                // all-lane EW (bias already in via x pad column); 7-trans cell update
                float g00 = hi ? acc[0][2] : acc[0][0];
                float g10 = hi ? acc[1][2] : acc[1][0];
                float g20 = hi ? acc[2][2] : acc[2][0];
                float g30 = hi ? acc[3][2] : acc[3][0];
                float g01 = hi ? acc[0][3] : acc[0][1];
                float g11 = hi ? acc[1][3] : acc[1][1];
                float g21 = hi ? acc[2][3] : acc[2][1];
                float g31 = hi ? acc[3][3] : acc[3][1];
                _Float16* hw = s_h0[n & 1];
                hw[off0] = (_Float16)cell_ew(g00, g10, g20, g30, cc0);
                hw[off1] = (_Float16)cell_ew(g01, g11, g21, g31, cc1);
                // hoist next step's x-part into the barrier shadow (x is stable
                // within a chunk; skip at chunk boundary where buffer is rewritten)
                if ((n & 15) != 15 && n + 1 < NT) {
                    const _Float16* xrow2 = s_x[((n + 1) >> 4) & 1] + (((n + 1) & 15) * BT + bA) * XPh;
                    f16x8 Ax2 = *(const f16x8*)(xrow2 + kq);
                    #pragma unroll
                    for (int t = 0; t < 4; ++t)
                        accx[t] = __builtin_amdgcn_mfma_f32_16x16x32_f16(Ax2, B0[t], z4, 0, 0, 0);
                }
            }
            if ((n & 15) == 15 && n + 1 < NT) {
                _Float16* dst = s_x[((n >> 4) + 1) & 1];
                xstoreh(dst, tid, pfA);
                if (tid < 384) xstoreh(dst, tid + NTH, pfB);
            }
            bar_lds();
        }
    } else {
        // ---- B fragments, layer1 (f16): chunks {h0[0:32), h0[32:64), h1[0:32), h1[32:64)} ----
        f16x8 B0[4], B1[4], B2[4], B3[4]; f32x4 bseed[4];
        #pragma unroll
        for (int t = 0; t < 4; ++t) {
            const int g = 64 * t + ue;
            const float bf = bih1[g] + bhh1[g];
            bseed[t] = (f32x4){ bf, bf, bf, bf };   // bias seeded as MFMA C-operand
            #pragma unroll
            for (int j = 0; j < 8; ++j) {
                int k = kq + j;
                B0[t][j] = (_Float16)Wih1[g * NH + k];
                B1[t][j] = (_Float16)Wih1[g * NH + 32 + k];
                B2[t][j] = (_Float16)Whh1[g * NH + k];
                B3[t][j] = (_Float16)Whh1[g * NH + 32 + k];
            }
        }
        #pragma unroll 1
        for (int n = 0; n <= NT; ++n) {
            if ((n & 15) == 0 && n + CH < NT) {
                pfA = xg4[gxi(tid, n + CH, b0)];
                if (tid < 384) pfB = xg4[gxi(tid + NTH, n + CH, b0)];
            }
            if (n >= 1) {
                const _Float16* h0r = s_h0[(n - 1) & 1] + bA * HPh;   // h0(n-1)
                const _Float16* h1r = s_h1[n & 1] + bA * HPh;         // h1(n-2)
                f16x8 A0 = *(const f16x8*)(h0r + kq);
                f16x8 A1 = *(const f16x8*)(h0r + 32 + kq);
                f16x8 A2 = *(const f16x8*)(h1r + kq);
                f16x8 A3 = *(const f16x8*)(h1r + 32 + kq);
                f32x4 accp[4], accq[4];
                #pragma unroll
                for (int t = 0; t < 4; ++t) {   // two independent depth-2 chains
                    f32x4 p = __builtin_amdgcn_mfma_f32_16x16x32_f16(A0, B0[t], bseed[t], 0, 0, 0);
                    accp[t] = __builtin_amdgcn_mfma_f32_16x16x32_f16(A1, B1[t], p, 0, 0, 0);
                    f32x4 q = __builtin_amdgcn_mfma_f32_16x16x32_f16(A2, B2[t], z4, 0, 0, 0);
                    accq[t] = __builtin_amdgcn_mfma_f32_16x16x32_f16(A3, B3[t], q, 0, 0, 0);
                }
                float g00 = (hi ? accp[0][2] : accp[0][0]) + (hi ? accq[0][2] : accq[0][0]);
                float g10 = (hi ? accp[1][2] : accp[1][0]) + (hi ? accq[1][2] : accq[1][0]);
                float g20 = (hi ? accp[2][2] : accp[2][0]) + (hi ? accq[2][2] : accq[2][0]);
                float g30 = (hi ? accp[3][2] : accp[3][0]) + (hi ? accq[3][2] : accq[3][0]);
                float g01 = (hi ? accp[0][3] : accp[0][1]) + (hi ? accq[0][3] : accq[0][1]);
                float g11 = (hi ? accp[1][3] : accp[1][1]) + (hi ? accq[1][3] : accq[1][1]);
                float g21 = (hi ? accp[2][3] : accp[2][1]) + (hi ? accq[2][3] : accq[2][1]);
                float g31 = (hi ? accp[3][3] : accp[3][1]) + (hi ? accq[3][3] : accq[3][1]);
                _Float16* hw = s_h1[(n - 1) & 1];
                float h0v = cell_ew(g00, g10, g20, g30, cc0);
                hw[off0] = (_Float16)h0v;
                float h1v = cell_ew(g01, g11, g21, g31, cc1);
                hw[off1] = (_Float16)h1v;
                if (n == NT) {
                    rlast[(size_t)(b0 + bm0) * NH + ue] = h0v;
                    rlast[(size_t)(b0 + bm1) * NH + ue] = h1v;
                    s_hf[bm0 * NH + ue] = h0v;
                    s_hf[bm1 * NH + ue] = h1v;
                }
            }
            if ((n & 15) == 15 && n + 1 < NT) {
                _Float16* dst = s_x[((n >> 4) + 1) & 1];
                xstoreh(dst, tid, pfA);
                if (tid < 384) xstoreh(dst, tid + NTH, pfB);
            }
            bar_lds();
        }
    }

    // ---------------- head: out = r_last @ Wout.T + bout ----------------
    if (tid < BT * 10) {
        int b = tid / 10, o = tid - 10 * (tid / 10);
        float a = bout[o];
        #pragma unroll
        for (int u = 0; u < NH; ++u) a += Wout[o * NH + u] * s_hf[b * NH + u];
        out[(size_t)(b0 + b) * 10 + o] = a;
    }
}

extern "C" void kernel_launch(void* const* d_in, const int* in_sizes, int n_in,
                              void* d_out, int out_size, void* d_ws, size_t ws_size,
                              hipStream_t stream) {
    const float* x    = (const float*)d_in[0];
    const float* Wih0 = (const float*)d_in[1];
    const float* Whh0 = (const float*)d_in[2];
    const float* bih0 = (const float*)d_in[3];
    const float* bhh0 = (const float*)d_in[4];
    const float* Wih1 = (const float*)d_in[5];
    const float* Whh1 = (const float*)d_in[6];
    const float* bih1 = (const float*)d_in[7];
    const float* bhh1 = (const float*)d_in[8];
    const float* Wout = (const float*)d_in[9];
    const float* bout = (const float*)d_in[10];

    const int B = in_sizes[0] / (NT * NI);      // 2048
    float* out   = (float*)d_out;               // [B,10]
    float* rlast = out + (size_t)B * 10;        // [B,64]

    dim3 grid(B / BT), block(NTH);              // 256 blocks -> 1 block/CU
    hipLaunchKernelGGL(lstm2_mfma, grid, block, 0, stream,
                       x, Wih0, Whh0, bih0, bhh0, Wih1, Whh1, bih1, bhh1,
                       Wout, bout, out, rlast);
}